// Round 2
// baseline (1260.686 us; speedup 1.0000x reference)
//
#include <hip/hip_runtime.h>
#include <hip/hip_bf16.h>

static constexpr int N_ = 50000;
static constexpr int E_ = 800000;

// ---------------- CSR build ----------------
__global__ void k_hist(const int* __restrict__ ei, int* __restrict__ deg) {
  int e = blockIdx.x * blockDim.x + threadIdx.x;
  if (e < E_) atomicAdd(&deg[ei[E_ + e]], 1);
}

__global__ __launch_bounds__(1024) void k_scan(const int* __restrict__ deg, int* __restrict__ off,
                                               int* __restrict__ cursor) {
  __shared__ int sm[1024];
  __shared__ int carry;
  int t = threadIdx.x;
  if (t == 0) carry = 0;
  __syncthreads();
  for (int base = 0; base < N_; base += 1024) {
    int i = base + t;
    int v = (i < N_) ? deg[i] : 0;
    sm[t] = v;
    __syncthreads();
    for (int s = 1; s < 1024; s <<= 1) {
      int u = (t >= s) ? sm[t - s] : 0;
      __syncthreads();
      sm[t] += u;
      __syncthreads();
    }
    int incl = sm[t] + carry;
    int excl = incl - v;
    if (i < N_) { off[i] = excl; cursor[i] = excl; }
    __syncthreads();
    if (t == 1023) carry = incl;
    __syncthreads();
  }
  if (t == 0) off[N_] = E_;
}

__global__ void k_scatter(const int* __restrict__ ei, int* __restrict__ cursor,
                          int* __restrict__ eidx) {
  int e = blockIdx.x * blockDim.x + threadIdx.x;
  if (e < E_) {
    int d = ei[E_ + e];
    int p = atomicAdd(&cursor[d], 1);
    eidx[p] = e;
  }
}

// ---------------- Encoder ----------------
__global__ __launch_bounds__(256) void k_encoder(
    const float* __restrict__ x, const int* __restrict__ ntype, const int* __restrict__ sid,
    const float* __restrict__ temb, const float* __restrict__ semb,
    const float* __restrict__ w1, const float* __restrict__ b1,
    const float* __restrict__ w2, const float* __restrict__ b2,
    float* __restrict__ hout) {
  __shared__ float w1s[23 * 64];
  __shared__ float w2s[64 * 64];
  __shared__ float b1s[64], b2s[64];
  __shared__ float tes[16], ses[32];
  for (int i = threadIdx.x; i < 23 * 64; i += blockDim.x) w1s[i] = w1[i];
  for (int i = threadIdx.x; i < 64 * 64; i += blockDim.x) w2s[i] = w2[i];
  if (threadIdx.x < 64) { b1s[threadIdx.x] = b1[threadIdx.x]; b2s[threadIdx.x] = b2[threadIdx.x]; }
  if (threadIdx.x < 16) tes[threadIdx.x] = temb[threadIdx.x];
  if (threadIdx.x < 32) ses[threadIdx.x] = semb[threadIdx.x];
  __syncthreads();
  int lane = threadIdx.x & 63;
  int wid = (blockIdx.x * blockDim.x + threadIdx.x) >> 6;
  int nw = (gridDim.x * blockDim.x) >> 6;
  for (int v = wid; v < N_; v += nw) {
    int nt = ntype[v], sd = sid[v];
    float in = 0.f;
    if (lane < 7) in = x[v * 7 + lane];
    else if (lane < 15) in = tes[nt * 8 + lane - 7];
    else if (lane < 23) in = ses[sd * 8 + lane - 15];
    float a = b1s[lane];
#pragma unroll
    for (int i = 0; i < 23; ++i) a += __shfl(in, i) * w1s[i * 64 + lane];
    a = fmaxf(a, 0.f);
    float b = b2s[lane];
    for (int i = 0; i < 64; ++i) b += __shfl(a, i) * w2s[i * 64 + lane];
    hout[v * 64 + lane] = b;
  }
}

// ---------------- GAT: node transforms ----------------
__global__ __launch_bounds__(256) void k_xlxr(
    const float* __restrict__ h,
    const float* __restrict__ wl, const float* __restrict__ bl,
    const float* __restrict__ wr, const float* __restrict__ br,
    float* __restrict__ xl, float* __restrict__ xr) {
  __shared__ float wls[64 * 64], wrs[64 * 64];
  __shared__ float bls[64], brs[64];
  for (int i = threadIdx.x; i < 64 * 64; i += blockDim.x) { wls[i] = wl[i]; wrs[i] = wr[i]; }
  if (threadIdx.x < 64) { bls[threadIdx.x] = bl[threadIdx.x]; brs[threadIdx.x] = br[threadIdx.x]; }
  __syncthreads();
  int lane = threadIdx.x & 63;
  int wid = (blockIdx.x * blockDim.x + threadIdx.x) >> 6;
  int nw = (gridDim.x * blockDim.x) >> 6;
  for (int v = wid; v < N_; v += nw) {
    float myh = h[v * 64 + lane];
    float al = bls[lane], ar = brs[lane];
    for (int i = 0; i < 64; ++i) {
      float hi = __shfl(myh, i);
      al += hi * wls[i * 64 + lane];
      ar += hi * wrs[i * 64 + lane];
    }
    xl[v * 64 + lane] = al;
    xr[v * 64 + lane] = ar;
  }
}

// ---------------- GAT: edge logits -> exp ----------------
__global__ __launch_bounds__(256) void k_edge(
    const int* __restrict__ ei, const float* __restrict__ eattr,
    const float* __restrict__ xl, const float* __restrict__ xr,
    const float* __restrict__ we, const float* __restrict__ att,
    float* __restrict__ ex) {
  __shared__ float wes[6 * 64];
  __shared__ float atts[64];
  for (int i = threadIdx.x; i < 6 * 64; i += blockDim.x) wes[i] = we[i];
  if (threadIdx.x < 64) atts[threadIdx.x] = att[threadIdx.x];
  __syncthreads();
  int lane = threadIdx.x & 63;
  int wid = (blockIdx.x * blockDim.x + threadIdx.x) >> 6;
  int nw = (gridDim.x * blockDim.x) >> 6;
  for (int e = wid; e < E_; e += nw) {
    int s = ei[e], d = ei[E_ + e];
    float xe = 0.f;
#pragma unroll
    for (int i = 0; i < 6; ++i) xe += eattr[e * 6 + i] * wes[i * 64 + lane];
    float m = xl[s * 64 + lane] + xr[d * 64 + lane] + xe;
    m = (m > 0.f) ? m : 0.2f * m;
    float t = m * atts[lane];
    t += __shfl_xor(t, 1);
    t += __shfl_xor(t, 2);
    t += __shfl_xor(t, 4);
    t += __shfl_xor(t, 8);
    if ((lane & 15) == 0) ex[e * 4 + (lane >> 4)] = expf(t);
  }
}

// ---------------- GAT: per-node aggregation (CSR, no float atomics) ----------------
template <bool RELU>
__global__ __launch_bounds__(256) void k_aggr(
    const int* __restrict__ ei, const int* __restrict__ off, const int* __restrict__ eidx,
    const float* __restrict__ xl, const float* __restrict__ ex,
    const float* __restrict__ bias,
    float* __restrict__ hout, float* __restrict__ den) {
  __shared__ float bs[64];
  if (threadIdx.x < 64) bs[threadIdx.x] = bias[threadIdx.x];
  __syncthreads();
  int lane = threadIdx.x & 63;
  int hd = lane >> 4;
  int wid = (blockIdx.x * blockDim.x + threadIdx.x) >> 6;
  int nw = (gridDim.x * blockDim.x) >> 6;
  for (int v = wid; v < N_; v += nw) {
    int p0 = off[v], p1 = off[v + 1];
    float acc = 0.f, dn = 0.f;
    for (int p = p0; p < p1; ++p) {
      int e = eidx[p];
      int s = ei[e];
      float xv = ex[e * 4 + hd];
      dn += xv;
      acc += xl[s * 64 + lane] * xv;
    }
    float o = acc / (dn + 1e-16f) + bs[lane];
    if (RELU) o = fmaxf(o, 0.f);
    hout[v * 64 + lane] = o;
    if ((lane & 15) == 0) den[v * 4 + hd] = dn;
  }
}

// ---------------- GAT: alpha write-out ----------------
__global__ void k_alpha(const int* __restrict__ ei, const float* __restrict__ ex,
                        const float* __restrict__ den, float* __restrict__ out) {
  int i = blockIdx.x * blockDim.x + threadIdx.x;
  if (i < E_ * 4) {
    int e = i >> 2, hd = i & 3;
    int d = ei[E_ + e];
    out[i] = ex[i] / (den[d * 4 + hd] + 1e-16f);
  }
}

// ---------------- GRU part 1: gi = h @ wih + bih ----------------
__global__ __launch_bounds__(256) void k_gru1(
    const float* __restrict__ h,
    const float* __restrict__ wih, const float* __restrict__ bih,
    float* __restrict__ gi) {
  __shared__ float wsm[64 * 192];  // 49KB
  __shared__ float bs[192];
  for (int i = threadIdx.x; i < 64 * 192; i += blockDim.x) wsm[i] = wih[i];
  for (int i = threadIdx.x; i < 192; i += blockDim.x) bs[i] = bih[i];
  __syncthreads();
  int lane = threadIdx.x & 63;
  int wid = (blockIdx.x * blockDim.x + threadIdx.x) >> 6;
  int nw = (gridDim.x * blockDim.x) >> 6;
  for (int v = wid; v < N_; v += nw) {
    float myh = h[v * 64 + lane];
    float gr = bs[lane], gz = bs[64 + lane], gn = bs[128 + lane];
    for (int i = 0; i < 64; ++i) {
      float hi = __shfl(myh, i);
      gr += hi * wsm[i * 192 + lane];
      gz += hi * wsm[i * 192 + 64 + lane];
      gn += hi * wsm[i * 192 + 128 + lane];
    }
    gi[v * 192 + lane] = gr;
    gi[v * 192 + 64 + lane] = gz;
    gi[v * 192 + 128 + lane] = gn;
  }
}

// ---------------- GRU part 2: gates ----------------
__global__ __launch_bounds__(256) void k_gru2(
    const float* __restrict__ hs, const float* __restrict__ gi,
    const float* __restrict__ whh, const float* __restrict__ bhh,
    float* __restrict__ nh, float* __restrict__ nhout) {
  __shared__ float wsm[64 * 192];  // 49KB
  __shared__ float bs[192];
  for (int i = threadIdx.x; i < 64 * 192; i += blockDim.x) wsm[i] = whh[i];
  for (int i = threadIdx.x; i < 192; i += blockDim.x) bs[i] = bhh[i];
  __syncthreads();
  int lane = threadIdx.x & 63;
  int wid = (blockIdx.x * blockDim.x + threadIdx.x) >> 6;
  int nw = (gridDim.x * blockDim.x) >> 6;
  for (int v = wid; v < N_; v += nw) {
    float mys = hs[v * 64 + lane];
    float hr = bs[lane], hz = bs[64 + lane], hn = bs[128 + lane];
    for (int i = 0; i < 64; ++i) {
      float si = __shfl(mys, i);
      hr += si * wsm[i * 192 + lane];
      hz += si * wsm[i * 192 + 64 + lane];
      hn += si * wsm[i * 192 + 128 + lane];
    }
    float gr = gi[v * 192 + lane];
    float gz = gi[v * 192 + 64 + lane];
    float gn = gi[v * 192 + 128 + lane];
    float r = 1.f / (1.f + expf(-(gr + hr)));
    float z = 1.f / (1.f + expf(-(gz + hz)));
    float n = tanhf(gn + r * hn);
    float o = (1.f - z) * n + z * mys;
    nh[v * 64 + lane] = o;
    nhout[v * 64 + lane] = o;
  }
}

// ---------------- Decoder ----------------
__global__ __launch_bounds__(256) void k_dec(
    const float* __restrict__ nh,
    const float* __restrict__ w1, const float* __restrict__ b1,
    const float* __restrict__ w2, const float* __restrict__ b2,
    float* __restrict__ out) {
  __shared__ float w1s[64 * 64];
  __shared__ float w2s[64 * 7];
  __shared__ float b1s[64], b2s[7];
  for (int i = threadIdx.x; i < 64 * 64; i += blockDim.x) w1s[i] = w1[i];
  for (int i = threadIdx.x; i < 64 * 7; i += blockDim.x) w2s[i] = w2[i];
  if (threadIdx.x < 64) b1s[threadIdx.x] = b1[threadIdx.x];
  if (threadIdx.x < 7) b2s[threadIdx.x] = b2[threadIdx.x];
  __syncthreads();
  int lane = threadIdx.x & 63;
  int wid = (blockIdx.x * blockDim.x + threadIdx.x) >> 6;
  int nw = (gridDim.x * blockDim.x) >> 6;
  for (int v = wid; v < N_; v += nw) {
    float myn = nh[v * 64 + lane];
    float d = b1s[lane];
    for (int i = 0; i < 64; ++i) d += __shfl(myn, i) * w1s[i * 64 + lane];
    d = fmaxf(d, 0.f);
    float o = (lane < 7) ? b2s[lane] : 0.f;
    for (int j = 0; j < 64; ++j) {
      float dj = __shfl(d, j);
      if (lane < 7) o += dj * w2s[j * 7 + lane];
    }
    if (lane < 7) out[v * 7 + lane] = o;
  }
}

extern "C" void kernel_launch(void* const* d_in, const int* in_sizes, int n_in,
                              void* d_out, int out_size, void* d_ws, size_t ws_size,
                              hipStream_t stream) {
  const float* x      = (const float*)d_in[0];
  const int* ntype    = (const int*)d_in[1];
  const int* sid      = (const int*)d_in[2];
  const int* ei       = (const int*)d_in[3];
  const float* eattr  = (const float*)d_in[4];
  const float* hs     = (const float*)d_in[5];
  const float* temb   = (const float*)d_in[6];
  const float* semb   = (const float*)d_in[7];
  const float* enc_w1 = (const float*)d_in[8];
  const float* enc_b1 = (const float*)d_in[9];
  const float* enc_w2 = (const float*)d_in[10];
  const float* enc_b2 = (const float*)d_in[11];
  const float* g1_wl  = (const float*)d_in[12];
  const float* g1_bl  = (const float*)d_in[13];
  const float* g1_wr  = (const float*)d_in[14];
  const float* g1_br  = (const float*)d_in[15];
  const float* g1_we  = (const float*)d_in[16];
  const float* g1_att = (const float*)d_in[17];
  const float* g1_bias= (const float*)d_in[18];
  const float* g2_wl  = (const float*)d_in[19];
  const float* g2_bl  = (const float*)d_in[20];
  const float* g2_wr  = (const float*)d_in[21];
  const float* g2_br  = (const float*)d_in[22];
  const float* g2_we  = (const float*)d_in[23];
  const float* g2_att = (const float*)d_in[24];
  const float* g2_bias= (const float*)d_in[25];
  const float* gru_wih= (const float*)d_in[26];
  const float* gru_bih= (const float*)d_in[27];
  const float* gru_whh= (const float*)d_in[28];
  const float* gru_bhh= (const float*)d_in[29];
  const float* dec_w1 = (const float*)d_in[30];
  const float* dec_b1 = (const float*)d_in[31];
  const float* dec_w2 = (const float*)d_in[32];
  const float* dec_b2 = (const float*)d_in[33];

  float* ws = (float*)d_ws;
  float* hA  = ws;               // N*64
  float* hB  = hA + N_ * 64;     // N*64   (also start of gi = N*192 spanning hB,xl,xr)
  float* xl  = hB + N_ * 64;     // N*64
  float* xr  = xl + N_ * 64;     // N*64
  float* ex  = xr + N_ * 64;     // E*4    (also nh f32 after GAT done: N*64 fits)
  float* den = ex + E_ * 4;      // N*4
  int* deg  = (int*)(den + N_ * 4); // N
  int* off  = deg + N_;             // N+1
  int* cur  = off + N_ + 1;         // N
  int* eidx = cur + N_;             // E

  float* gi = hB;   // N*192 floats, spans hB|xl|xr (free at GRU time)
  float* nh = ex;   // N*64 floats (free after k_alpha L2)

  float* out0  = (float*)d_out;      // N*7
  float* outnh = out0 + N_ * 7;      // N*64
  float* outa1 = outnh + N_ * 64;    // E*4
  float* outa2 = outa1 + E_ * 4;     // E*4

  hipMemsetAsync(deg, 0, N_ * sizeof(int), stream);
  k_hist<<<(E_ + 255) / 256, 256, 0, stream>>>(ei, deg);
  k_scan<<<1, 1024, 0, stream>>>(deg, off, cur);
  k_scatter<<<(E_ + 255) / 256, 256, 0, stream>>>(ei, cur, eidx);

  k_encoder<<<1024, 256, 0, stream>>>(x, ntype, sid, temb, semb,
                                      enc_w1, enc_b1, enc_w2, enc_b2, hA);
  // GAT layer 1: hA -> hB (relu)
  k_xlxr<<<2048, 256, 0, stream>>>(hA, g1_wl, g1_bl, g1_wr, g1_br, xl, xr);
  k_edge<<<4096, 256, 0, stream>>>(ei, eattr, xl, xr, g1_we, g1_att, ex);
  k_aggr<true><<<4096, 256, 0, stream>>>(ei, off, eidx, xl, ex, g1_bias, hB, den);
  k_alpha<<<(E_ * 4 + 255) / 256, 256, 0, stream>>>(ei, ex, den, outa1);
  // GAT layer 2: hB -> hA (no relu)
  k_xlxr<<<2048, 256, 0, stream>>>(hB, g2_wl, g2_bl, g2_wr, g2_br, xl, xr);
  k_edge<<<4096, 256, 0, stream>>>(ei, eattr, xl, xr, g2_we, g2_att, ex);
  k_aggr<false><<<4096, 256, 0, stream>>>(ei, off, eidx, xl, ex, g2_bias, hA, den);
  k_alpha<<<(E_ * 4 + 255) / 256, 256, 0, stream>>>(ei, ex, den, outa2);
  // GRU (two-stage; gi overwrites hB|xl|xr which are now free)
  k_gru1<<<1024, 256, 0, stream>>>(hA, gru_wih, gru_bih, gi);
  k_gru2<<<1024, 256, 0, stream>>>(hs, gi, gru_whh, gru_bhh, nh, outnh);
  // Decoder
  k_dec<<<1024, 256, 0, stream>>>(nh, dec_w1, dec_b1, dec_w2, dec_b2, out0);
}

// Round 3
// 953.217 us; speedup vs baseline: 1.3226x; 1.3226x over previous
//
#include <hip/hip_runtime.h>
#include <hip/hip_bf16.h>

static constexpr int N_ = 50000;
static constexpr int E_ = 800000;
static constexpr int CAP = 128;   // per-wave LDS edge cache (max degree fast-path)

// ---------------- CSR build ----------------
__global__ void k_hist(const int* __restrict__ ei, int* __restrict__ deg) {
  int e = blockIdx.x * blockDim.x + threadIdx.x;
  if (e < E_) atomicAdd(&deg[ei[E_ + e]], 1);
}

// two-level scan: per-block exclusive scan + block sums
__global__ __launch_bounds__(1024) void k_scan_blk(const int* __restrict__ deg,
                                                   int* __restrict__ off,
                                                   int* __restrict__ bsum) {
  __shared__ int sm[1024];
  int t = threadIdx.x;
  int i = blockIdx.x * 1024 + t;
  int v = (i < N_) ? deg[i] : 0;
  sm[t] = v;
  __syncthreads();
  for (int s = 1; s < 1024; s <<= 1) {
    int u = (t >= s) ? sm[t - s] : 0;
    __syncthreads();
    sm[t] += u;
    __syncthreads();
  }
  if (i < N_) off[i] = sm[t] - v;           // exclusive, pre-block-offset
  if (t == 1023) bsum[blockIdx.x] = sm[t];  // block total
}

__global__ void k_scan_top(int* __restrict__ bsum, int nb) {
  int t = threadIdx.x;  // 64 threads
  int v = (t < nb) ? bsum[t] : 0;
  int orig = v;
  for (int s = 1; s < 64; s <<= 1) {
    int u = __shfl_up(v, s);
    if (t >= s) v += u;
  }
  if (t < nb) bsum[t] = v - orig;  // exclusive
}

__global__ void k_scan_add(int* __restrict__ off, const int* __restrict__ bsum,
                           int* __restrict__ cur) {
  int i = blockIdx.x * blockDim.x + threadIdx.x;
  if (i < N_) {
    int o = off[i] + bsum[i >> 10];
    off[i] = o;
    cur[i] = o;
  }
  if (i == 0) off[N_] = E_;
}

// scatter: CSR position + (edge id, src) pairs for contiguous fused reads
__global__ void k_scatter(const int* __restrict__ ei, int* __restrict__ cursor,
                          int2* __restrict__ csr_es) {
  int e = blockIdx.x * blockDim.x + threadIdx.x;
  if (e < E_) {
    int s = ei[e];
    int d = ei[E_ + e];
    int p = atomicAdd(&cursor[d], 1);
    csr_es[p] = make_int2(e, s);
  }
}

// ---------------- Encoder ----------------
__global__ __launch_bounds__(256) void k_encoder(
    const float* __restrict__ x, const int* __restrict__ ntype, const int* __restrict__ sid,
    const float* __restrict__ temb, const float* __restrict__ semb,
    const float* __restrict__ w1, const float* __restrict__ b1,
    const float* __restrict__ w2, const float* __restrict__ b2,
    float* __restrict__ hout) {
  __shared__ float w1s[23 * 64];
  __shared__ float w2s[64 * 64];
  __shared__ float b1s[64], b2s[64];
  __shared__ float tes[16], ses[32];
  for (int i = threadIdx.x; i < 23 * 64; i += blockDim.x) w1s[i] = w1[i];
  for (int i = threadIdx.x; i < 64 * 64; i += blockDim.x) w2s[i] = w2[i];
  if (threadIdx.x < 64) { b1s[threadIdx.x] = b1[threadIdx.x]; b2s[threadIdx.x] = b2[threadIdx.x]; }
  if (threadIdx.x < 16) tes[threadIdx.x] = temb[threadIdx.x];
  if (threadIdx.x < 32) ses[threadIdx.x] = semb[threadIdx.x];
  __syncthreads();
  int lane = threadIdx.x & 63;
  int wid = (blockIdx.x * blockDim.x + threadIdx.x) >> 6;
  int nw = (gridDim.x * blockDim.x) >> 6;
  for (int v = wid; v < N_; v += nw) {
    int nt = ntype[v], sd = sid[v];
    float in = 0.f;
    if (lane < 7) in = x[v * 7 + lane];
    else if (lane < 15) in = tes[nt * 8 + lane - 7];
    else if (lane < 23) in = ses[sd * 8 + lane - 15];
    float a = b1s[lane];
#pragma unroll
    for (int i = 0; i < 23; ++i) a += __shfl(in, i) * w1s[i * 64 + lane];
    a = fmaxf(a, 0.f);
    float b = b2s[lane];
    for (int i = 0; i < 64; ++i) b += __shfl(a, i) * w2s[i * 64 + lane];
    hout[v * 64 + lane] = b;
  }
}

// ---------------- GAT: node transforms ----------------
__global__ __launch_bounds__(256) void k_xlxr(
    const float* __restrict__ h,
    const float* __restrict__ wl, const float* __restrict__ bl,
    const float* __restrict__ wr, const float* __restrict__ br,
    float* __restrict__ xl, float* __restrict__ xr) {
  __shared__ float wls[64 * 64], wrs[64 * 64];
  __shared__ float bls[64], brs[64];
  for (int i = threadIdx.x; i < 64 * 64; i += blockDim.x) { wls[i] = wl[i]; wrs[i] = wr[i]; }
  if (threadIdx.x < 64) { bls[threadIdx.x] = bl[threadIdx.x]; brs[threadIdx.x] = br[threadIdx.x]; }
  __syncthreads();
  int lane = threadIdx.x & 63;
  int wid = (blockIdx.x * blockDim.x + threadIdx.x) >> 6;
  int nw = (gridDim.x * blockDim.x) >> 6;
  for (int v = wid; v < N_; v += nw) {
    float myh = h[v * 64 + lane];
    float al = bls[lane], ar = brs[lane];
    for (int i = 0; i < 64; ++i) {
      float hi = __shfl(myh, i);
      al += hi * wls[i * 64 + lane];
      ar += hi * wrs[i * 64 + lane];
    }
    xl[v * 64 + lane] = al;
    xr[v * 64 + lane] = ar;
  }
}

// ---------------- Fused GAT edge+softmax+aggregate+alpha ----------------
template <bool RELU>
__global__ __launch_bounds__(256) void k_fused(
    const int* __restrict__ off, const int2* __restrict__ csr_es,
    const float* __restrict__ eattr,
    const float* __restrict__ xl, const float* __restrict__ xr,
    const float* __restrict__ we, const float* __restrict__ att,
    const float* __restrict__ bias,
    float* __restrict__ hout, float* __restrict__ alpha) {
  __shared__ float wes[6 * 64];
  __shared__ float atts[64];
  __shared__ float bs[64];
  __shared__ float exbuf[4][CAP * 4];  // per-wave: CAP edges x 4 heads
  __shared__ int ebuf[4][CAP];
  for (int i = threadIdx.x; i < 6 * 64; i += blockDim.x) wes[i] = we[i];
  if (threadIdx.x < 64) { atts[threadIdx.x] = att[threadIdx.x]; bs[threadIdx.x] = bias[threadIdx.x]; }
  __syncthreads();
  int lane = threadIdx.x & 63;
  int wv = threadIdx.x >> 6;
  int hd = lane >> 4;
  int wid = (blockIdx.x * blockDim.x + threadIdx.x) >> 6;
  int nw = (gridDim.x * blockDim.x) >> 6;
  for (int v = wid; v < N_; v += nw) {
    int p0 = off[v], p1 = off[v + 1];
    int cnt = p1 - p0;
    float xr_d = xr[v * 64 + lane];
    float den = 0.f, num = 0.f;
    int2 es = (cnt > 0) ? csr_es[p0] : make_int2(0, 0);
    for (int p = p0; p < p1; ++p) {
      int e = es.x, s = es.y;
      if (p + 1 < p1) es = csr_es[p + 1];  // prefetch next indices
      float ea = (lane < 6) ? eattr[e * 6 + lane] : 0.f;
      float xls = xl[s * 64 + lane];
      float m = xls + xr_d;
#pragma unroll
      for (int i = 0; i < 6; ++i) m += __shfl(ea, i) * wes[i * 64 + lane];
      m = (m > 0.f) ? m : 0.2f * m;
      float t = m * atts[lane];
      t += __shfl_xor(t, 1);
      t += __shfl_xor(t, 2);
      t += __shfl_xor(t, 4);
      t += __shfl_xor(t, 8);
      float ex = expf(t);     // per-lane: this head's ex (replicated x16)
      den += ex;
      num = fmaf(xls, ex, num);
      int idx = p - p0;
      if (idx < CAP) {
        if ((lane & 15) == 0) exbuf[wv][idx * 4 + hd] = ex;
        if (lane == 0) ebuf[wv][idx] = e;
      }
    }
    float o = num / (den + 1e-16f) + bs[lane];
    if (RELU) o = fmaxf(o, 0.f);
    hout[v * 64 + lane] = o;
    // alpha write-out: 16 edges/iter, lane -> (edge = lane>>2, head = lane&3)
    float dinv = 1.f / (den + 1e-16f);
    float dh = __shfl(dinv, (lane & 3) << 4);  // den of head (lane&3)
    if (cnt <= CAP) {
      for (int base = 0; base < cnt; base += 16) {
        int idx = base + (lane >> 2);
        if (idx < cnt) {
          float exv = exbuf[wv][idx * 4 + (lane & 3)];
          int e = ebuf[wv][idx];
          alpha[e * 4 + (lane & 3)] = exv * dh;
        }
      }
    } else {
      // wave-uniform fallback (degree > CAP): recompute collectively (never hit w/ avg deg 16)
      for (int p = p0; p < p1; ++p) {
        int2 es2 = csr_es[p];
        int e = es2.x, s = es2.y;
        float ea = (lane < 6) ? eattr[e * 6 + lane] : 0.f;
        float m = xl[s * 64 + lane] + xr_d;
#pragma unroll
        for (int i = 0; i < 6; ++i) m += __shfl(ea, i) * wes[i * 64 + lane];
        m = (m > 0.f) ? m : 0.2f * m;
        float t = m * atts[lane];
        t += __shfl_xor(t, 1);
        t += __shfl_xor(t, 2);
        t += __shfl_xor(t, 4);
        t += __shfl_xor(t, 8);
        if ((lane & 15) == 0) alpha[e * 4 + hd] = expf(t) * dinv;
      }
    }
  }
}

// ---------------- GRU part 1: gi = h @ wih + bih ----------------
__global__ __launch_bounds__(256) void k_gru1(
    const float* __restrict__ h,
    const float* __restrict__ wih, const float* __restrict__ bih,
    float* __restrict__ gi) {
  __shared__ float wsm[64 * 192];  // 49KB
  __shared__ float bs[192];
  for (int i = threadIdx.x; i < 64 * 192; i += blockDim.x) wsm[i] = wih[i];
  for (int i = threadIdx.x; i < 192; i += blockDim.x) bs[i] = bih[i];
  __syncthreads();
  int lane = threadIdx.x & 63;
  int wid = (blockIdx.x * blockDim.x + threadIdx.x) >> 6;
  int nw = (gridDim.x * blockDim.x) >> 6;
  for (int v = wid; v < N_; v += nw) {
    float myh = h[v * 64 + lane];
    float gr = bs[lane], gz = bs[64 + lane], gn = bs[128 + lane];
    for (int i = 0; i < 64; ++i) {
      float hi = __shfl(myh, i);
      gr += hi * wsm[i * 192 + lane];
      gz += hi * wsm[i * 192 + 64 + lane];
      gn += hi * wsm[i * 192 + 128 + lane];
    }
    gi[v * 192 + lane] = gr;
    gi[v * 192 + 64 + lane] = gz;
    gi[v * 192 + 128 + lane] = gn;
  }
}

// ---------------- GRU part 2: gates ----------------
__global__ __launch_bounds__(256) void k_gru2(
    const float* __restrict__ hs, const float* __restrict__ gi,
    const float* __restrict__ whh, const float* __restrict__ bhh,
    float* __restrict__ nh, float* __restrict__ nhout) {
  __shared__ float wsm[64 * 192];  // 49KB
  __shared__ float bs[192];
  for (int i = threadIdx.x; i < 64 * 192; i += blockDim.x) wsm[i] = whh[i];
  for (int i = threadIdx.x; i < 192; i += blockDim.x) bs[i] = bhh[i];
  __syncthreads();
  int lane = threadIdx.x & 63;
  int wid = (blockIdx.x * blockDim.x + threadIdx.x) >> 6;
  int nw = (gridDim.x * blockDim.x) >> 6;
  for (int v = wid; v < N_; v += nw) {
    float mys = hs[v * 64 + lane];
    float hr = bs[lane], hz = bs[64 + lane], hn = bs[128 + lane];
    for (int i = 0; i < 64; ++i) {
      float si = __shfl(mys, i);
      hr += si * wsm[i * 192 + lane];
      hz += si * wsm[i * 192 + 64 + lane];
      hn += si * wsm[i * 192 + 128 + lane];
    }
    float gr = gi[v * 192 + lane];
    float gz = gi[v * 192 + 64 + lane];
    float gn = gi[v * 192 + 128 + lane];
    float r = 1.f / (1.f + expf(-(gr + hr)));
    float z = 1.f / (1.f + expf(-(gz + hz)));
    float n = tanhf(gn + r * hn);
    float o = (1.f - z) * n + z * mys;
    nh[v * 64 + lane] = o;
    nhout[v * 64 + lane] = o;
  }
}

// ---------------- Decoder ----------------
__global__ __launch_bounds__(256) void k_dec(
    const float* __restrict__ nh,
    const float* __restrict__ w1, const float* __restrict__ b1,
    const float* __restrict__ w2, const float* __restrict__ b2,
    float* __restrict__ out) {
  __shared__ float w1s[64 * 64];
  __shared__ float w2s[64 * 7];
  __shared__ float b1s[64], b2s[7];
  for (int i = threadIdx.x; i < 64 * 64; i += blockDim.x) w1s[i] = w1[i];
  for (int i = threadIdx.x; i < 64 * 7; i += blockDim.x) w2s[i] = w2[i];
  if (threadIdx.x < 64) b1s[threadIdx.x] = b1[threadIdx.x];
  if (threadIdx.x < 7) b2s[threadIdx.x] = b2[threadIdx.x];
  __syncthreads();
  int lane = threadIdx.x & 63;
  int wid = (blockIdx.x * blockDim.x + threadIdx.x) >> 6;
  int nw = (gridDim.x * blockDim.x) >> 6;
  for (int v = wid; v < N_; v += nw) {
    float myn = nh[v * 64 + lane];
    float d = b1s[lane];
    for (int i = 0; i < 64; ++i) d += __shfl(myn, i) * w1s[i * 64 + lane];
    d = fmaxf(d, 0.f);
    float o = (lane < 7) ? b2s[lane] : 0.f;
    for (int j = 0; j < 64; ++j) {
      float dj = __shfl(d, j);
      if (lane < 7) o += dj * w2s[j * 7 + lane];
    }
    if (lane < 7) out[v * 7 + lane] = o;
  }
}

extern "C" void kernel_launch(void* const* d_in, const int* in_sizes, int n_in,
                              void* d_out, int out_size, void* d_ws, size_t ws_size,
                              hipStream_t stream) {
  const float* x      = (const float*)d_in[0];
  const int* ntype    = (const int*)d_in[1];
  const int* sid      = (const int*)d_in[2];
  const int* ei       = (const int*)d_in[3];
  const float* eattr  = (const float*)d_in[4];
  const float* hs     = (const float*)d_in[5];
  const float* temb   = (const float*)d_in[6];
  const float* semb   = (const float*)d_in[7];
  const float* enc_w1 = (const float*)d_in[8];
  const float* enc_b1 = (const float*)d_in[9];
  const float* enc_w2 = (const float*)d_in[10];
  const float* enc_b2 = (const float*)d_in[11];
  const float* g1_wl  = (const float*)d_in[12];
  const float* g1_bl  = (const float*)d_in[13];
  const float* g1_wr  = (const float*)d_in[14];
  const float* g1_br  = (const float*)d_in[15];
  const float* g1_we  = (const float*)d_in[16];
  const float* g1_att = (const float*)d_in[17];
  const float* g1_bias= (const float*)d_in[18];
  const float* g2_wl  = (const float*)d_in[19];
  const float* g2_bl  = (const float*)d_in[20];
  const float* g2_wr  = (const float*)d_in[21];
  const float* g2_br  = (const float*)d_in[22];
  const float* g2_we  = (const float*)d_in[23];
  const float* g2_att = (const float*)d_in[24];
  const float* g2_bias= (const float*)d_in[25];
  const float* gru_wih= (const float*)d_in[26];
  const float* gru_bih= (const float*)d_in[27];
  const float* gru_whh= (const float*)d_in[28];
  const float* gru_bhh= (const float*)d_in[29];
  const float* dec_w1 = (const float*)d_in[30];
  const float* dec_b1 = (const float*)d_in[31];
  const float* dec_w2 = (const float*)d_in[32];
  const float* dec_b2 = (const float*)d_in[33];

  float* ws = (float*)d_ws;
  float* hA = ws;               // N*64
  float* hB = hA + N_ * 64;     // N*64
  float* xl = hB + N_ * 64;     // N*64
  float* xr = xl + N_ * 64;     // N*64
  int* deg  = (int*)(xr + N_ * 64);  // N
  int* off  = deg + N_;              // N+1
  int* cur  = off + N_ + 1;          // N
  int* bsum = cur + N_;              // 64 (padded, keeps csr_es 8B-aligned)
  int2* csr_es = (int2*)(bsum + 64); // E pairs

  float* gi = hB;   // N*192 spans hB|xl|xr (free at GRU time)
  float* nh = hA;   // reuse hA after gru1 consumed it... gru2 writes here

  float* out0  = (float*)d_out;      // N*7
  float* outnh = out0 + N_ * 7;      // N*64
  float* outa1 = outnh + N_ * 64;    // E*4
  float* outa2 = outa1 + E_ * 4;     // E*4

  const int NB_SCAN = (N_ + 1023) / 1024;  // 49

  hipMemsetAsync(deg, 0, N_ * sizeof(int), stream);
  k_hist<<<(E_ + 255) / 256, 256, 0, stream>>>(ei, deg);
  k_scan_blk<<<NB_SCAN, 1024, 0, stream>>>(deg, off, bsum);
  k_scan_top<<<1, 64, 0, stream>>>(bsum, NB_SCAN);
  k_scan_add<<<(N_ + 255) / 256, 256, 0, stream>>>(off, bsum, cur);
  k_scatter<<<(E_ + 255) / 256, 256, 0, stream>>>(ei, cur, csr_es);

  k_encoder<<<1024, 256, 0, stream>>>(x, ntype, sid, temb, semb,
                                      enc_w1, enc_b1, enc_w2, enc_b2, hA);
  // GAT layer 1: hA -> hB (relu)
  k_xlxr<<<2048, 256, 0, stream>>>(hA, g1_wl, g1_bl, g1_wr, g1_br, xl, xr);
  k_fused<true><<<4096, 256, 0, stream>>>(off, csr_es, eattr, xl, xr,
                                          g1_we, g1_att, g1_bias, hB, outa1);
  // GAT layer 2: hB -> hA (no relu)
  k_xlxr<<<2048, 256, 0, stream>>>(hB, g2_wl, g2_bl, g2_wr, g2_br, xl, xr);
  k_fused<false><<<4096, 256, 0, stream>>>(off, csr_es, eattr, xl, xr,
                                           g2_we, g2_att, g2_bias, hA, outa2);
  // GRU (gi overwrites hB|xl|xr which are now free; gru1 reads hA first)
  k_gru1<<<1024, 256, 0, stream>>>(hA, gru_wih, gru_bih, gi);
  k_gru2<<<1024, 256, 0, stream>>>(hs, gi, gru_whh, gru_bhh, nh, outnh);
  // Decoder
  k_dec<<<1024, 256, 0, stream>>>(nh, dec_w1, dec_b1, dec_w2, dec_b2, out0);
}